// Round 7
// baseline (3672.997 us; speedup 1.0000x reference)
//
#include <hip/hip_runtime.h>
#include <stdint.h>

#define B_ 32
#define T_ 128
#define S_ 256
#define D_ 1024
#define V_ 10000

typedef unsigned short u16;
typedef unsigned long long u64;
typedef __attribute__((ext_vector_type(8))) short bf16x8;   // 8 bf16 in 4 VGPRs
typedef __attribute__((ext_vector_type(4))) float f32x4;

__device__ __forceinline__ float bf2f(u16 u){ union { unsigned int i; float f; } v; v.i = ((unsigned int)u)<<16; return v.f; }
__device__ __forceinline__ u16 f2bf(float f){ union { float ff; unsigned int i; } v; v.ff = f; unsigned int x = v.i; return (u16)((x + 0x7fffu + ((x>>16)&1u))>>16); }
// fast inf-safe activations: hardware rcp (1 trans) instead of precise div (~10 VALU).
// x->+inf: e=inf -> rcp(inf)=0 -> tanh=1, sigm=1. x->-inf: e=0 -> tanh=-1, sigm=0. No clamps needed.
__device__ __forceinline__ float ftanh(float x){
  float e = __expf(2.f*x);
  return __builtin_fmaf(-2.f, __builtin_amdgcn_rcpf(1.f+e), 1.f);
}
__device__ __forceinline__ float sigm(float x){
  return __builtin_amdgcn_rcpf(1.f + __expf(-x));
}

// ---------------- prep kernels ----------------
__global__ void k_cast(const float* __restrict__ in, u16* __restrict__ out, long n){
  for (long i = (long)blockIdx.x*blockDim.x + threadIdx.x; i < n; i += (long)gridDim.x*blockDim.x)
    out[i] = f2bf(in[i]);
}

__global__ void k_w1cat(const float* __restrict__ wih1, const float* __restrict__ whh1, u16* __restrict__ out){
  const long n = (long)4096*2048;
  for (long i = (long)blockIdx.x*blockDim.x + threadIdx.x; i < n; i += (long)gridDim.x*blockDim.x){
    int row = (int)(i >> 11), k = (int)(i & 2047);
    float v = (k < D_) ? wih1[(size_t)row*D_ + k] : whh1[(size_t)row*D_ + (k - D_)];
    out[i] = f2bf(v);
  }
}

__global__ void k_bias(const float* __restrict__ bih, const float* __restrict__ bhh,
                       const float* __restrict__ bcv, const float* __restrict__ abias,
                       const float* __restrict__ Wcv, const float* __restrict__ fcw,
                       float* __restrict__ bias0, float* __restrict__ bias1,
                       float* __restrict__ biasE, float* __restrict__ convw){
  int i = blockIdx.x*blockDim.x + threadIdx.x;
  if (i < 4096){ bias0[i] = bih[i]+bhh[i]; bias1[i] = bih[4096+i]+bhh[4096+i]; }
  if (i < 1024){
    biasE[i] = bcv[i]+abias[i];
    convw[i*4+0]=Wcv[i*3+0]; convw[i*4+1]=Wcv[i*3+1]; convw[i*4+2]=Wcv[i*3+2]; convw[i*4+3]=fcw[i];
  }
}

__global__ void k_gather(const float* __restrict__ emb, const int* __restrict__ tgt, u16* __restrict__ embA){
  int row = blockIdx.x;            // row = t*32 + b
  int t = row >> 5, b = row & 31;
  int e = tgt[b*T_ + t];
  const float* src = emb + (size_t)e*D_;
  u16* dst = embA + (size_t)row*D_;
  for (int d = threadIdx.x; d < D_; d += 256) dst[d] = f2bf(src[d]);
}

// ---------------- big MFMA GEMM: C = A(M x K, lda) @ B(N x K)^T (+bias)(+act) ----------------
__device__ __forceinline__ void gld_lds(const u16* g, u16* l){
  __builtin_amdgcn_global_load_lds((const __attribute__((address_space(1))) unsigned int*)g,
                                   (__attribute__((address_space(3))) unsigned int*)l, 16, 0, 0);
}

template<int OUT_MODE, bool SWIZ>   // OUT_MODE: 0 f32, 1 bf16, 2 tanh->bf16 ; SWIZ: row(t*32+b)->(b*128+t)
__global__ __launch_bounds__(256) void k_gemm128(const u16* __restrict__ Am, const u16* __restrict__ Bm,
      const float* __restrict__ bias, void* __restrict__ Cout, int M, int N, int K, int lda, int ldc)
{
  __shared__ u16 As[128*32];
  __shared__ u16 Bs[128*32];
  int bm = blockIdx.y*128, bn = blockIdx.x*128;
  int tid = threadIdx.x;
  int wv = tid>>6, lane = tid&63;
  int wm = (wv>>1)*64, wn = (wv&1)*64;
  int r = lane&15, kh = lane>>4;
  f32x4 zero = {0.f,0.f,0.f,0.f};
  f32x4 acc[4][4];
  #pragma unroll
  for (int mi=0;mi<4;mi++)
    #pragma unroll
    for (int ni=0;ni<4;ni++) acc[mi][ni] = zero;

  for (int k0 = 0; k0 < K; k0 += 32){
    #pragma unroll
    for (int i=0;i<2;i++){
      int c = tid + i*256;
      int row = c>>2, ko = (c&3)*8;
      int ga = bm+row; if (ga > M-1) ga = M-1;
      gld_lds(Am + (size_t)ga*lda + k0 + ko, As + c*8);
      int gb = bn+row; if (gb > N-1) gb = N-1;
      gld_lds(Bm + (size_t)gb*K + k0 + ko, Bs + c*8);
    }
    __syncthreads();
    bf16x8 af[4], bfv[4];
    #pragma unroll
    for (int mi=0;mi<4;mi++) af[mi]  = *(const bf16x8*)(As + (wm+mi*16+r)*32 + kh*8);
    #pragma unroll
    for (int ni=0;ni<4;ni++) bfv[ni] = *(const bf16x8*)(Bs + (wn+ni*16+r)*32 + kh*8);
    #pragma unroll
    for (int mi=0;mi<4;mi++)
      #pragma unroll
      for (int ni=0;ni<4;ni++)
        acc[mi][ni] = __builtin_amdgcn_mfma_f32_16x16x32_bf16(af[mi], bfv[ni], acc[mi][ni], 0,0,0);
    __syncthreads();
  }
  #pragma unroll
  for (int mi=0;mi<4;mi++)
    #pragma unroll
    for (int ni=0;ni<4;ni++)
      #pragma unroll
      for (int rr=0;rr<4;rr++){
        int grow = bm+wm+mi*16+kh*4+rr;
        int gcol = bn+wn+ni*16+r;
        if (grow < M && gcol < N){
          float v = acc[mi][ni][rr];
          if (bias) v += bias[gcol];
          size_t orow = SWIZ ? (size_t)((grow&31)*T_ + (grow>>5)) : (size_t)grow;
          if (OUT_MODE==0)      ((float*)Cout)[orow*(size_t)ldc + gcol] = v;
          else if (OUT_MODE==1) ((u16*)Cout)[orow*(size_t)ldc + gcol] = f2bf(v);
          else                  ((u16*)Cout)[orow*(size_t)ldc + gcol] = f2bf(ftanh(v));
        }
      }
}

// ---------------- hierarchical fence-free barrier (256 blocks) ----------------
__device__ __forceinline__ void xcd_barrier(int* barL, int it){
  asm volatile("s_waitcnt vmcnt(0)" ::: "memory");
  __syncthreads();
  if (threadIdx.x==0){
    int grp = blockIdx.x & 7;
    int* gcnt = barL + grp*32;
    int* root = barL + 256;
    int* rel  = barL + 320 + grp*32;
    int v = __hip_atomic_fetch_add(gcnt, 1, __ATOMIC_RELAXED, __HIP_MEMORY_SCOPE_AGENT);
    if (v == 32*(it+1) - 1){                    // last of my group this iteration
      int rv = __hip_atomic_fetch_add(root, 1, __ATOMIC_RELAXED, __HIP_MEMORY_SCOPE_AGENT);
      if (rv == 8*(it+1) - 1){                  // last group overall -> release all
        #pragma unroll
        for (int g2=0; g2<8; ++g2)
          __hip_atomic_store(barL + 320 + g2*32, it+1, __ATOMIC_RELAXED, __HIP_MEMORY_SCOPE_AGENT);
      }
    }
    while (__hip_atomic_load(rel, __ATOMIC_RELAXED, __HIP_MEMORY_SCOPE_AGENT) < it+1)
      __builtin_amdgcn_s_sleep(8);
  }
  __syncthreads();
}

// ---------------- small-group barrier (attention: 8 blocks/batch, own cache line) ----------------
__device__ __forceinline__ void ring_barrier(int* cnt, int nblk, int it){
  asm volatile("s_waitcnt vmcnt(0)" ::: "memory");
  __syncthreads();
  if (threadIdx.x==0){
    __hip_atomic_fetch_add(cnt, 1, __ATOMIC_RELAXED, __HIP_MEMORY_SCOPE_AGENT);
    int target = nblk*(it+1);
    while (__hip_atomic_load(cnt, __ATOMIC_RELAXED, __HIP_MEMORY_SCOPE_AGENT) < target)
      __builtin_amdgcn_s_sleep(4);
  }
  __syncthreads();
}

// ---------------- persistent LSTM: weights resident in LDS, 1 barrier/step ----------------
__global__ __launch_bounds__(512) void k_lstm_p(const u16* __restrict__ Whh0, const u16* __restrict__ W1cat,
    const u16* __restrict__ X0, const float* __restrict__ bias1,
    u16* __restrict__ Hh, u16* __restrict__ qcat, int* __restrict__ barL)
{
  __shared__ u16 W0s[16*1024];     // 32 KB  (16 out-rows x K=1024, 16B-chunk XOR swizzle)
  __shared__ u16 W1s[16*2048];     // 64 KB  (16 out-rows x K=2048)
  __shared__ float gl0[8*512];     // 16 KB  8-wave partials, layer0
  __shared__ float gl1[8*512];     // 16 KB  layer1
  __shared__ u16 hb0[128];
  __shared__ u16 hb1[128];
  int bid = blockIdx.x, tid = threadIdx.x;
  int w = tid>>6, lane = tid&63, r = lane&15, kh = lane>>4;
  // ---- stage this block's weight slice into LDS once ----
  for (int ci = tid; ci < 2048; ci += 512){
    int row = ci>>7, c = ci&127;
    int grow = (row>>2)*1024 + bid*4 + (row&3);          // gate-major row in Whh0
    bf16x8 v = *(const bf16x8*)(Whh0 + (size_t)grow*1024 + c*8);
    *(bf16x8*)(W0s + (size_t)(((row<<7) + (c ^ (row&7)))*8)) = v;
  }
  for (int ci = tid; ci < 4096; ci += 512){
    int row = ci>>8, c = ci&255;
    int grow = (row>>2)*1024 + bid*4 + (row&3);
    bf16x8 v = *(const bf16x8*)(W1cat + (size_t)grow*2048 + c*8);
    *(bf16x8*)(W1s + (size_t)(((row<<8) + (c ^ (row&7)))*8)) = v;
  }
  __syncthreads();
  float c0reg = 0.f, c1reg = 0.f;
  int cb = tid>>2, cj = tid&3;            // (tid<128): cell (batch cb, local col cj)
  int col = bid*4 + cj;
  float b1i=0.f, b1f=0.f, b1g=0.f, b1o=0.f;
  if (tid < 128){ b1i=bias1[col]; b1f=bias1[1024+col]; b1g=bias1[2048+col]; b1o=bias1[3072+col]; }
  for (int p = 0; p <= T_; ++p){
    const u16* Hprev = Hh + (size_t)p*65536;       // slot p-1
    u16* Hcur = (u16*)Hh + (size_t)(p+1)*65536;    // slot p
    bool doG0 = (p < T_), doG1 = (p > 0);
    // ---- prefetch X0 gate terms early (hides scattered LLC reads under MFMA) ----
    float x_gi=0.f, x_gf=0.f, x_gg=0.f, x_go=0.f;
    if (doG0 && tid < 128){
      const u16* xr = X0 + ((size_t)p*32 + cb)*4096 + col;
      x_gi = bf2f(xr[0]); x_gf = bf2f(xr[1024]); x_gg = bf2f(xr[2048]); x_go = bf2f(xr[3072]);
    }
    f32x4 acc00={0.f,0.f,0.f,0.f}, acc01={0.f,0.f,0.f,0.f};
    f32x4 acc10={0.f,0.f,0.f,0.f}, acc11={0.f,0.f,0.f,0.f};
    bf16x8 a_g0[2][4], a_g1[2][8];
    // ---- issue ALL A-loads up front (normal cached loads, L2-served broadcast) ----
    if (doG0){
      const u16* a0 = Hprev + (size_t)r*2048 + w*128 + kh*8;
      const u16* a1 = Hprev + (size_t)(16+r)*2048 + w*128 + kh*8;
      #pragma unroll
      for (int kk=0;kk<4;kk++){ a_g0[0][kk] = *(const bf16x8*)(a0 + kk*32);
                                a_g0[1][kk] = *(const bf16x8*)(a1 + kk*32); }
    }
    if (doG1){
      const u16* a0 = Hprev + (size_t)r*2048 + w*256 + kh*8;
      const u16* a1 = Hprev + (size_t)(16+r)*2048 + w*256 + kh*8;
      #pragma unroll
      for (int kk=0;kk<8;kk++){ a_g1[0][kk] = *(const bf16x8*)(a0 + kk*32);
                                a_g1[1][kk] = *(const bf16x8*)(a1 + kk*32); }
    }
    // ---- MFMA from LDS weights ----
    if (doG0){
      #pragma unroll
      for (int kk=0;kk<4;kk++){
        int c = (w<<4) + (kk<<2) + kh;
        bf16x8 bv = *(const bf16x8*)(W0s + (size_t)((((int)r<<7) + (c ^ (r&7)))*8));
        acc00 = __builtin_amdgcn_mfma_f32_16x16x32_bf16(a_g0[0][kk], bv, acc00, 0,0,0);
        acc01 = __builtin_amdgcn_mfma_f32_16x16x32_bf16(a_g0[1][kk], bv, acc01, 0,0,0);
      }
    }
    if (doG1){
      #pragma unroll
      for (int kk=0;kk<8;kk++){
        int c = (w<<5) + (kk<<2) + kh;
        bf16x8 bv = *(const bf16x8*)(W1s + (size_t)((((int)r<<8) + (c ^ (r&7)))*8));
        acc10 = __builtin_amdgcn_mfma_f32_16x16x32_bf16(a_g1[0][kk], bv, acc10, 0,0,0);
        acc11 = __builtin_amdgcn_mfma_f32_16x16x32_bf16(a_g1[1][kk], bv, acc11, 0,0,0);
      }
    }
    // ---- one-sync cross-wave reduce + cells ----
    #pragma unroll
    for (int rr=0;rr<4;rr++){
      gl0[w*512 + (kh*4+rr)*16 + r]    = acc00[rr];
      gl0[w*512 + (16+kh*4+rr)*16 + r] = acc01[rr];
      gl1[w*512 + (kh*4+rr)*16 + r]    = acc10[rr];
      gl1[w*512 + (16+kh*4+rr)*16 + r] = acc11[rr];
    }
    __syncthreads();
    if (tid < 128){
      if (doG0){
        float gi=x_gi, gf=x_gf, gg=x_gg, go=x_go;
        #pragma unroll
        for (int ww=0;ww<8;ww++){
          const float* gp = gl0 + ww*512 + cb*16 + cj;
          gi += gp[0]; gf += gp[4]; gg += gp[8]; go += gp[12];
        }
        float cn = sigm(gf)*c0reg + sigm(gi)*ftanh(gg);
        float hn = sigm(go)*ftanh(cn); c0reg = cn;
        hb0[tid] = f2bf(hn);
      }
      if (doG1){
        float gi=b1i, gf=b1f, gg=b1g, go=b1o;
        #pragma unroll
        for (int ww=0;ww<8;ww++){
          const float* gp = gl1 + ww*512 + cb*16 + cj;
          gi += gp[0]; gf += gp[4]; gg += gp[8]; go += gp[12];
        }
        float cn = sigm(gf)*c1reg + sigm(gi)*ftanh(gg);
        float hn = sigm(go)*ftanh(cn); c1reg = cn;
        hb1[tid] = f2bf(hn);
      }
    }
    __syncthreads();
    // ---- packed coherent h stores + q output (tid<32, one u64 each) ----
    if (tid < 32){
      union { u64 v; u16 s[4]; } pk;
      if (doG0){
        pk.s[0]=hb0[tid*4]; pk.s[1]=hb0[tid*4+1]; pk.s[2]=hb0[tid*4+2]; pk.s[3]=hb0[tid*4+3];
        __hip_atomic_store((u64*)(Hcur + (size_t)tid*2048 + bid*4), pk.v,
                           __ATOMIC_RELAXED, __HIP_MEMORY_SCOPE_AGENT);
      }
      if (doG1){
        pk.s[0]=hb1[tid*4]; pk.s[1]=hb1[tid*4+1]; pk.s[2]=hb1[tid*4+2]; pk.s[3]=hb1[tid*4+3];
        __hip_atomic_store((u64*)(Hcur + (size_t)tid*2048 + 1024 + bid*4), pk.v,
                           __ATOMIC_RELAXED, __HIP_MEMORY_SCOPE_AGENT);
        *(u64*)(qcat + ((size_t)(p-1)*32 + tid)*2048 + bid*4) = pk.v;   // q, normal store
      }
    }
    if (p < T_) xcd_barrier(barL, p);
  }
}

// ---------------- persistent attention: 8 blocks/batch x 1024 thr, 1 barrier/step ----------------
__global__ __launch_bounds__(1024) void k_attn_p(const u16* __restrict__ vpb, const u16* __restrict__ qpb,
    const u16* __restrict__ enc, const float* __restrict__ convw,
    float* __restrict__ eng, u16* __restrict__ qcat, int* __restrict__ barA)
{
  __shared__ float aw[256];
  __shared__ float red[16];
  __shared__ float cred[1024];
  int bid = blockIdx.x, tid = threadIdx.x;
  int b = bid>>3, p = bid&7;
  int w = tid>>6, lane = tid&63;
  int d0 = lane*16;
  f32x4 cw[16];
  #pragma unroll
  for (int j=0;j<16;j++) cw[j] = *(const f32x4*)(convw + (size_t)(d0+j)*4);
  if (tid < 256) aw[tid] = 0.f;
  __syncthreads();
  int* cnt = barA + b*32;
  for (int t=0; t<T_; ++t){
    float* ebuf = eng + (t&1)*8192 + b*256;
    // ---- energy: 16 waves x 2 s each covers s in [p*32, p*32+32) ----
    const u16* qrow = qpb + ((size_t)t*32 + b)*1024 + d0;
    bf16x8 q0 = *(const bf16x8*)qrow, q1 = *(const bf16x8*)(qrow+8);
    float qf[16];
    #pragma unroll
    for (int j=0;j<16;j++) qf[j] = bf2f((u16)(j<8 ? q0[j] : q1[j-8]));
    #pragma unroll
    for (int ss=0; ss<2; ++ss){
      int s = p*32 + w*2 + ss;
      float am = (s>0)   ? aw[s-1] : 0.f;
      float ac =           aw[s];
      float ap = (s<255) ? aw[s+1] : 0.f;
      const u16* vrow = vpb + ((size_t)(b*256+s))*1024 + d0;
      bf16x8 v0 = *(const bf16x8*)vrow, v1 = *(const bf16x8*)(vrow+8);
      float sum = 0.f;
      #pragma unroll
      for (int j=0;j<16;j++){
        float vv = bf2f((u16)(j<8 ? v0[j] : v1[j-8]));
        float x = qf[j] + vv + am*cw[j][0] + ac*cw[j][1] + ap*cw[j][2];
        sum += ftanh(x)*cw[j][3];
      }
      #pragma unroll
      for (int o=32;o;o>>=1) sum += __shfl_xor(sum, o);
      if (lane==0)
        __hip_atomic_store(ebuf + s, sum, __ATOMIC_RELAXED, __HIP_MEMORY_SCOPE_AGENT);
    }
    ring_barrier(cnt, 8, t);
    // ---- softmax over 256 (waves 0-3, redundant per block) ----
    float e_val = -3.0e38f;
    if (tid < 256)
      e_val = __hip_atomic_load(ebuf + tid, __ATOMIC_RELAXED, __HIP_MEMORY_SCOPE_AGENT);
    float m = e_val;
    #pragma unroll
    for (int o=32;o;o>>=1) m = fmaxf(m, __shfl_xor(m,o));
    if (w < 4 && lane==0) red[w] = m;
    __syncthreads();
    float mx = fmaxf(fmaxf(red[0],red[1]),fmaxf(red[2],red[3]));
    float ex = (tid < 256) ? __expf(e_val - mx) : 0.f;
    float sl = ex;
    #pragma unroll
    for (int o=32;o;o>>=1) sl += __shfl_xor(sl,o);
    __syncthreads();
    if (w < 4 && lane==0) red[8+w] = sl;
    __syncthreads();
    float st = red[8]+red[9]+red[10]+red[11];
    if (tid < 256) aw[tid] = ex * __builtin_amdgcn_rcpf(st);
    __syncthreads();
    // ---- context: d-cols [p*128, p*128+128), 8-way s-split ----
    int sq = tid>>7, dt = tid&127;
    const u16* ep = enc + (size_t)(b*256 + sq*32)*1024 + p*128 + dt;
    float a0=0.f,a1=0.f,a2=0.f,a3=0.f;
    #pragma unroll 4
    for (int s2=0;s2<32;s2+=4){
      a0 += aw[sq*32+s2]   * bf2f(ep[(size_t)(s2)  *1024]);
      a1 += aw[sq*32+s2+1] * bf2f(ep[(size_t)(s2+1)*1024]);
      a2 += aw[sq*32+s2+2] * bf2f(ep[(size_t)(s2+2)*1024]);
      a3 += aw[sq*32+s2+3] * bf2f(ep[(size_t)(s2+3)*1024]);
    }
    cred[tid] = a0+a1+a2+a3;
    __syncthreads();
    if (tid < 128){
      float c = 0.f;
      #pragma unroll
      for (int q2=0;q2<8;q2++) c += cred[q2*128 + tid];
      qcat[((size_t)t*32 + b)*2048 + 1024 + p*128 + tid] = f2bf(c);
    }
    __syncthreads();
  }
}

// in-place log_softmax over V per row of out (register-cached, 2 passes of traffic)
__global__ __launch_bounds__(256) void k_logsm(float* __restrict__ out){
  int row = blockIdx.x, tid = threadIdx.x;
  float* p = out + (size_t)row*V_;
  __shared__ float red[4];
  float pv[40];
  int nv = 0;
  float mx = -3.0e38f;
  for (int v=tid; v<V_; v+=256){ float x = p[v]; pv[nv++] = x; mx = fmaxf(mx, x); }
  #pragma unroll
  for (int o=32;o;o>>=1) mx = fmaxf(mx, __shfl_xor(mx,o));
  if ((tid&63)==0) red[tid>>6]=mx;
  __syncthreads();
  mx = fmaxf(fmaxf(red[0],red[1]),fmaxf(red[2],red[3]));
  __syncthreads();
  float s = 0.f;
  for (int i=0;i<nv;i++) s += __expf(pv[i]-mx);
  #pragma unroll
  for (int o=32;o;o>>=1) s += __shfl_xor(s,o);
  if ((tid&63)==0) red[tid>>6]=s;
  __syncthreads();
  float lz = mx + __logf(red[0]+red[1]+red[2]+red[3]);
  { int i=0; for (int v=tid; v<V_; v+=256) p[v] = pv[i++] - lz; }
}

// ---------------- host ----------------
extern "C" void kernel_launch(void* const* d_in, const int* in_sizes, int n_in,
                              void* d_out, int out_size, void* d_ws, size_t ws_size,
                              hipStream_t stream)
{
  const float* enc   = (const float*)d_in[0];
  const int*   tgt   = (const int*)  d_in[1];
  const float* emb   = (const float*)d_in[2];
  const float* Wih   = (const float*)d_in[3];
  const float* Whh   = (const float*)d_in[4];
  const float* bih   = (const float*)d_in[5];
  const float* bhh   = (const float*)d_in[6];
  const float* Wcv   = (const float*)d_in[7];
  const float* bcv   = (const float*)d_in[8];
  const float* Wq    = (const float*)d_in[9];
  const float* Wvm   = (const float*)d_in[10];
  const float* abias = (const float*)d_in[11];
  const float* fcw   = (const float*)d_in[12];
  // d_in[13] fc_attn_b: softmax-invariant, unused
  const float* fc1w  = (const float*)d_in[14];
  const float* fc1b  = (const float*)d_in[15];
  const float* fc2w  = (const float*)d_in[16];
  const float* fc2b  = (const float*)d_in[17];
  float* out = (float*)d_out;

  char* base = (char*)d_ws; size_t off = 0;
  auto A = [&](size_t nbytes)->char*{ char* q = base + off; off += (nbytes + 255) & ~(size_t)255; return q; };
  u16* enc_bf  = (u16*)A(8388608ull*2);
  u16* Wv_bf   = (u16*)A(1048576ull*2);
  u16* Wih0_bf = (u16*)A(4194304ull*2);
  u16* W1cat   = (u16*)A(8388608ull*2);
  u16* Whh0_bf = (u16*)A(4194304ull*2);
  u16* Wq_bf   = (u16*)A(1048576ull*2);
  u16* fc1w_bf = (u16*)A(2097152ull*2);
  u16* fc2w_bf = (u16*)A(10240000ull*2);  // ALSO aliased as Hh during the LSTM phase
  u16* embA    = (u16*)A(4194304ull*2);   // reused: X0-GEMM A -> qpb -> hid
  u16* X0      = (u16*)A(16777216ull*2);  // (T*32, 4096) bf16, includes bias0
  u16* vpb     = (u16*)A(8388608ull*2);   // bf16(vproj + bconv + attn_bias)
  u16* qcat    = (u16*)A(8388608ull*2);   // (T*32, 2048) = [q | context]
  float* bias0 = (float*)A(4096*4);
  float* bias1 = (float*)A(4096*4);
  float* biasE = (float*)A(1024*4);
  float* convw = (float*)A(4096*4);       // [d][{Wc0,Wc1,Wc2,fcw}]
  float* eng   = (float*)A(2*8192*4);     // attn energy double buffer
  int* barL    = (int*)A(4096);           // hierarchical barrier, 128B-padded lines
  int* barA    = (int*)A(4096);           // 32 batches x 32-int (128B) lines
  u16* Hh      = fc2w_bf;                 // 130 slots x (32x2048) bf16 = 17.04 MB <= 20.48 MB
  u16* qpb     = embA;                    // (T*32, 1024) bf16 qp
  u16* hid     = embA;

  // zero h-history slots -1 and 0 + barriers (re-done on every graph replay)
  hipMemsetAsync(Hh, 0, 2*65536*2, stream);
  hipMemsetAsync(barL, 0, 4096, stream);
  hipMemsetAsync(barA, 0, 4096, stream);

  // prep: bf16 casts (fc2w cast DEFERRED until after LSTM+attn; its buffer holds Hh now)
  k_cast<<<2048,256,0,stream>>>(enc,  enc_bf,  8388608);
  k_cast<<<1024,256,0,stream>>>(Wih,  Wih0_bf, 4194304);
  k_cast<<<1024,256,0,stream>>>(Whh,  Whh0_bf, 4194304);
  k_cast<<<512,256,0,stream>>>(Wq,    Wq_bf,   1048576);
  k_cast<<<512,256,0,stream>>>(Wvm,   Wv_bf,   1048576);
  k_cast<<<512,256,0,stream>>>(fc1w,  fc1w_bf, 2097152);
  k_w1cat<<<2048,256,0,stream>>>(Wih + 4194304, Whh + 4194304, W1cat);
  k_bias<<<16,256,0,stream>>>(bih, bhh, bcv, abias, Wcv, fcw, bias0, bias1, biasE, convw);
  k_gather<<<4096,256,0,stream>>>(emb, tgt, embA);

  // vpb = bf16(enc @ Wv^T + (bconv + attn_bias))   (8192 x 1024 x 1024)
  k_gemm128<1,false><<<dim3(8,64),256,0,stream>>>(enc_bf, Wv_bf, biasE, vpb, 8192, 1024, 1024, 1024, 1024);
  // X0 = bf16(emb[targets] @ W_ih0^T + (b_ih0+b_hh0))  (4096 x 4096 x 1024)
  k_gemm128<1,false><<<dim3(32,32),256,0,stream>>>(embA, Wih0_bf, bias0, X0, 4096, 4096, 1024, 1024, 4096);

  // ---- persistent LSTM loop (256 blocks, weights in LDS, hierarchical barrier) ----
  {
    const u16* a0 = Whh0_bf; const u16* a1 = W1cat; const u16* a2 = X0; const float* a3 = bias1;
    u16* a4 = Hh; u16* a5 = qcat; int* a6 = barL;
    void* args[] = {(void*)&a0,(void*)&a1,(void*)&a2,(void*)&a3,(void*)&a4,(void*)&a5,(void*)&a6};
    hipError_t e = hipLaunchCooperativeKernel((const void*)k_lstm_p, dim3(256), dim3(512), args, 0, stream);
    if (e != hipSuccess)
      k_lstm_p<<<dim3(256),dim3(512),0,stream>>>(a0,a1,a2,a3,a4,a5,a6);
  }

  // qp for all steps: (4096 x 1024 x 1024), A = qcat[:, :1024] (lda 2048) -> bf16 qpb
  k_gemm128<1,false><<<dim3(8,32),256,0,stream>>>(qcat, Wq_bf, nullptr, qpb, 4096, 1024, 1024, 2048, 1024);

  // ---- persistent attention loop (256 blocks x 1024 thr, per-batch barrier) ----
  {
    const u16* a0 = vpb; const u16* a1 = qpb; const u16* a2 = enc_bf; const float* a3 = convw;
    float* a4 = eng; u16* a5 = qcat; int* a6 = barA;
    void* args[] = {(void*)&a0,(void*)&a1,(void*)&a2,(void*)&a3,(void*)&a4,(void*)&a5,(void*)&a6};
    hipError_t e = hipLaunchCooperativeKernel((const void*)k_attn_p, dim3(256), dim3(1024), args, 0, stream);
    if (e != hipSuccess)
      k_attn_p<<<dim3(256),dim3(1024),0,stream>>>(a0,a1,a2,a3,a4,a5,a6);
  }

  // hid = tanh(qcat @ fc1w^T + fc1b)   (4096 x 1024 x 2048)
  k_gemm128<2,false><<<dim3(8,32),256,0,stream>>>(qcat, fc1w_bf, fc1b, hid, 4096, 1024, 2048, 2048, 1024);
  // fc2 weight cast (deferred; Hh no longer needed)
  k_cast<<<2048,256,0,stream>>>(fc2w, fc2w_bf, 10240000);
  // logits = hid @ fc2w^T + fc2b -> out[b][t][v]  (4096 x 10000 x 1024, row swizzle (t,b)->(b,t))
  k_gemm128<0,true><<<dim3(79,32),256,0,stream>>>(hid, fc2w_bf, fc2b, out, 4096, V_, 1024, 1024, V_);
  // in-place log_softmax over V
  k_logsm<<<4096,256,0,stream>>>(out);
}

// Round 9
// 2790.981 us; speedup vs baseline: 1.3160x; 1.3160x over previous
//
#include <hip/hip_runtime.h>
#include <stdint.h>

#define B_ 32
#define T_ 128
#define S_ 256
#define D_ 1024
#define V_ 10000

typedef unsigned short u16;
typedef unsigned long long u64;
typedef __attribute__((ext_vector_type(8))) short bf16x8;   // 8 bf16 in 4 VGPRs
typedef __attribute__((ext_vector_type(4))) float f32x4;

__device__ __forceinline__ float bf2f(u16 u){ union { unsigned int i; float f; } v; v.i = ((unsigned int)u)<<16; return v.f; }
__device__ __forceinline__ u16 f2bf(float f){ union { float ff; unsigned int i; } v; v.ff = f; unsigned int x = v.i; return (u16)((x + 0x7fffu + ((x>>16)&1u))>>16); }
// fast inf-safe activations: hardware rcp (1 trans) instead of precise div (~10 VALU).
// x->+inf: e=inf -> rcp(inf)=0 -> tanh=1, sigm=1. x->-inf: e=0 -> tanh=-1, sigm=0.
__device__ __forceinline__ float ftanh(float x){
  float e = __expf(2.f*x);
  return __builtin_fmaf(-2.f, __builtin_amdgcn_rcpf(1.f+e), 1.f);
}
__device__ __forceinline__ float sigm(float x){
  return __builtin_amdgcn_rcpf(1.f + __expf(-x));
}

// ---------------- prep kernels ----------------
__global__ void k_cast(const float* __restrict__ in, u16* __restrict__ out, long n){
  for (long i = (long)blockIdx.x*blockDim.x + threadIdx.x; i < n; i += (long)gridDim.x*blockDim.x)
    out[i] = f2bf(in[i]);
}

__global__ void k_w1cat(const float* __restrict__ wih1, const float* __restrict__ whh1, u16* __restrict__ out){
  const long n = (long)4096*2048;
  for (long i = (long)blockIdx.x*blockDim.x + threadIdx.x; i < n; i += (long)gridDim.x*blockDim.x){
    int row = (int)(i >> 11), k = (int)(i & 2047);
    float v = (k < D_) ? wih1[(size_t)row*D_ + k] : whh1[(size_t)row*D_ + (k - D_)];
    out[i] = f2bf(v);
  }
}

__global__ void k_bias(const float* __restrict__ bih, const float* __restrict__ bhh,
                       const float* __restrict__ bcv, const float* __restrict__ abias,
                       const float* __restrict__ Wcv, const float* __restrict__ fcw,
                       float* __restrict__ bias0, float* __restrict__ bias1,
                       float* __restrict__ biasE, float* __restrict__ convw){
  int i = blockIdx.x*blockDim.x + threadIdx.x;
  if (i < 4096){ bias0[i] = bih[i]+bhh[i]; bias1[i] = bih[4096+i]+bhh[4096+i]; }
  if (i < 1024){
    biasE[i] = bcv[i]+abias[i];
    convw[i*4+0]=Wcv[i*3+0]; convw[i*4+1]=Wcv[i*3+1]; convw[i*4+2]=Wcv[i*3+2]; convw[i*4+3]=fcw[i];
  }
}

__global__ void k_gather(const float* __restrict__ emb, const int* __restrict__ tgt, u16* __restrict__ embA){
  int row = blockIdx.x;            // row = t*32 + b
  int t = row >> 5, b = row & 31;
  int e = tgt[b*T_ + t];
  const float* src = emb + (size_t)e*D_;
  u16* dst = embA + (size_t)row*D_;
  for (int d = threadIdx.x; d < D_; d += 256) dst[d] = f2bf(src[d]);
}

// ---------------- big MFMA GEMM: C = A(M x K, lda) @ B(N x K)^T (+bias)(+act) ----------------
__device__ __forceinline__ void gld_lds(const u16* g, u16* l){
  __builtin_amdgcn_global_load_lds((const __attribute__((address_space(1))) unsigned int*)g,
                                   (__attribute__((address_space(3))) unsigned int*)l, 16, 0, 0);
}

template<int OUT_MODE, bool SWIZ>   // OUT_MODE: 0 f32, 1 bf16, 2 tanh->bf16 ; SWIZ: row(t*32+b)->(b*128+t)
__global__ __launch_bounds__(256) void k_gemm128(const u16* __restrict__ Am, const u16* __restrict__ Bm,
      const float* __restrict__ bias, void* __restrict__ Cout, int M, int N, int K, int lda, int ldc)
{
  __shared__ u16 As[128*32];
  __shared__ u16 Bs[128*32];
  int bm = blockIdx.y*128, bn = blockIdx.x*128;
  int tid = threadIdx.x;
  int wv = tid>>6, lane = tid&63;
  int wm = (wv>>1)*64, wn = (wv&1)*64;
  int r = lane&15, kh = lane>>4;
  f32x4 zero = {0.f,0.f,0.f,0.f};
  f32x4 acc[4][4];
  #pragma unroll
  for (int mi=0;mi<4;mi++)
    #pragma unroll
    for (int ni=0;ni<4;ni++) acc[mi][ni] = zero;

  for (int k0 = 0; k0 < K; k0 += 32){
    #pragma unroll
    for (int i=0;i<2;i++){
      int c = tid + i*256;
      int row = c>>2, ko = (c&3)*8;
      int ga = bm+row; if (ga > M-1) ga = M-1;
      gld_lds(Am + (size_t)ga*lda + k0 + ko, As + c*8);
      int gb = bn+row; if (gb > N-1) gb = N-1;
      gld_lds(Bm + (size_t)gb*K + k0 + ko, Bs + c*8);
    }
    __syncthreads();
    bf16x8 af[4], bfv[4];
    #pragma unroll
    for (int mi=0;mi<4;mi++) af[mi]  = *(const bf16x8*)(As + (wm+mi*16+r)*32 + kh*8);
    #pragma unroll
    for (int ni=0;ni<4;ni++) bfv[ni] = *(const bf16x8*)(Bs + (wn+ni*16+r)*32 + kh*8);
    #pragma unroll
    for (int mi=0;mi<4;mi++)
      #pragma unroll
      for (int ni=0;ni<4;ni++)
        acc[mi][ni] = __builtin_amdgcn_mfma_f32_16x16x32_bf16(af[mi], bfv[ni], acc[mi][ni], 0,0,0);
    __syncthreads();
  }
  #pragma unroll
  for (int mi=0;mi<4;mi++)
    #pragma unroll
    for (int ni=0;ni<4;ni++)
      #pragma unroll
      for (int rr=0;rr<4;rr++){
        int grow = bm+wm+mi*16+kh*4+rr;
        int gcol = bn+wn+ni*16+r;
        if (grow < M && gcol < N){
          float v = acc[mi][ni][rr];
          if (bias) v += bias[gcol];
          size_t orow = SWIZ ? (size_t)((grow&31)*T_ + (grow>>5)) : (size_t)grow;
          if (OUT_MODE==0)      ((float*)Cout)[orow*(size_t)ldc + gcol] = v;
          else if (OUT_MODE==1) ((u16*)Cout)[orow*(size_t)ldc + gcol] = f2bf(v);
          else                  ((u16*)Cout)[orow*(size_t)ldc + gcol] = f2bf(ftanh(v));
        }
      }
}

// ---------------- hierarchical fence-free barrier (256 blocks) ----------------
__device__ __forceinline__ void xcd_barrier(int* barL, int it){
  asm volatile("s_waitcnt vmcnt(0)" ::: "memory");
  __syncthreads();
  if (threadIdx.x==0){
    int grp = blockIdx.x & 7;
    int* gcnt = barL + grp*32;
    int* root = barL + 256;
    int* rel  = barL + 320 + grp*32;
    int v = __hip_atomic_fetch_add(gcnt, 1, __ATOMIC_RELAXED, __HIP_MEMORY_SCOPE_AGENT);
    if (v == 32*(it+1) - 1){                    // last of my group this iteration
      int rv = __hip_atomic_fetch_add(root, 1, __ATOMIC_RELAXED, __HIP_MEMORY_SCOPE_AGENT);
      if (rv == 8*(it+1) - 1){                  // last group overall -> release all
        #pragma unroll
        for (int g2=0; g2<8; ++g2)
          __hip_atomic_store(barL + 320 + g2*32, it+1, __ATOMIC_RELAXED, __HIP_MEMORY_SCOPE_AGENT);
      }
    }
    while (__hip_atomic_load(rel, __ATOMIC_RELAXED, __HIP_MEMORY_SCOPE_AGENT) < it+1)
      __builtin_amdgcn_s_sleep(8);
  }
  __syncthreads();
}

// ---------------- small-group barrier (attention: 8 blocks/batch, own cache line) ----------------
__device__ __forceinline__ void ring_barrier(int* cnt, int nblk, int it){
  asm volatile("s_waitcnt vmcnt(0)" ::: "memory");
  __syncthreads();
  if (threadIdx.x==0){
    __hip_atomic_fetch_add(cnt, 1, __ATOMIC_RELAXED, __HIP_MEMORY_SCOPE_AGENT);
    int target = nblk*(it+1);
    while (__hip_atomic_load(cnt, __ATOMIC_RELAXED, __HIP_MEMORY_SCOPE_AGENT) < target)
      __builtin_amdgcn_s_sleep(4);
  }
  __syncthreads();
}

// ---------------- persistent LSTM: weights resident in LDS, 1 barrier/step ----------------
__global__ __launch_bounds__(512) void k_lstm_p(const u16* __restrict__ Whh0, const u16* __restrict__ W1cat,
    const u16* __restrict__ X0, const float* __restrict__ bias1,
    u16* __restrict__ Hh, u16* __restrict__ qcat, int* __restrict__ barL)
{
  __shared__ u16 W0s[16*1024];     // 32 KB  (16 out-rows x K=1024, 16B-chunk XOR swizzle)
  __shared__ u16 W1s[16*2048];     // 64 KB  (16 out-rows x K=2048)
  __shared__ float gl0[8*512];     // 16 KB  8-wave partials, layer0
  __shared__ float gl1[8*512];     // 16 KB  layer1
  __shared__ u16 hb0[128];
  __shared__ u16 hb1[128];
  int bid = blockIdx.x, tid = threadIdx.x;
  int w = tid>>6, lane = tid&63, r = lane&15, kh = lane>>4;
  // ---- stage this block's weight slice into LDS once ----
  for (int ci = tid; ci < 2048; ci += 512){
    int row = ci>>7, c = ci&127;
    int grow = (row>>2)*1024 + bid*4 + (row&3);          // gate-major row in Whh0
    bf16x8 v = *(const bf16x8*)(Whh0 + (size_t)grow*1024 + c*8);
    *(bf16x8*)(W0s + (size_t)(((row<<7) + (c ^ (row&7)))*8)) = v;
  }
  for (int ci = tid; ci < 4096; ci += 512){
    int row = ci>>8, c = ci&255;
    int grow = (row>>2)*1024 + bid*4 + (row&3);
    bf16x8 v = *(const bf16x8*)(W1cat + (size_t)grow*2048 + c*8);
    *(bf16x8*)(W1s + (size_t)(((row<<8) + (c ^ (row&7)))*8)) = v;
  }
  __syncthreads();
  float c0reg = 0.f, c1reg = 0.f;
  int cb = tid>>2, cj = tid&3;            // (tid<128): cell (batch cb, local col cj)
  int col = bid*4 + cj;
  float b1i=0.f, b1f=0.f, b1g=0.f, b1o=0.f;
  if (tid < 128){ b1i=bias1[col]; b1f=bias1[1024+col]; b1g=bias1[2048+col]; b1o=bias1[3072+col]; }
  for (int p = 0; p <= T_; ++p){
    const u16* Hprev = Hh + (size_t)p*65536;       // slot p-1
    u16* Hcur = (u16*)Hh + (size_t)(p+1)*65536;    // slot p
    bool doG0 = (p < T_), doG1 = (p > 0);
    // ---- prefetch X0 gate terms early (hides scattered LLC reads under MFMA) ----
    float x_gi=0.f, x_gf=0.f, x_gg=0.f, x_go=0.f;
    if (doG0 && tid < 128){
      const u16* xr = X0 + ((size_t)p*32 + cb)*4096 + col;
      x_gi = bf2f(xr[0]); x_gf = bf2f(xr[1024]); x_gg = bf2f(xr[2048]); x_go = bf2f(xr[3072]);
    }
    f32x4 acc00={0.f,0.f,0.f,0.f}, acc01={0.f,0.f,0.f,0.f};
    f32x4 acc10={0.f,0.f,0.f,0.f}, acc11={0.f,0.f,0.f,0.f};
    bf16x8 a_g0[2][4], a_g1[2][8];
    // ---- issue ALL A-loads up front (normal cached loads, L2-served broadcast) ----
    if (doG0){
      const u16* a0 = Hprev + (size_t)r*2048 + w*128 + kh*8;
      const u16* a1 = Hprev + (size_t)(16+r)*2048 + w*128 + kh*8;
      #pragma unroll
      for (int kk=0;kk<4;kk++){ a_g0[0][kk] = *(const bf16x8*)(a0 + kk*32);
                                a_g0[1][kk] = *(const bf16x8*)(a1 + kk*32); }
    }
    if (doG1){
      const u16* a0 = Hprev + (size_t)r*2048 + w*256 + kh*8;
      const u16* a1 = Hprev + (size_t)(16+r)*2048 + w*256 + kh*8;
      #pragma unroll
      for (int kk=0;kk<8;kk++){ a_g1[0][kk] = *(const bf16x8*)(a0 + kk*32);
                                a_g1[1][kk] = *(const bf16x8*)(a1 + kk*32); }
    }
    // ---- MFMA from LDS weights ----
    if (doG0){
      #pragma unroll
      for (int kk=0;kk<4;kk++){
        int c = (w<<4) + (kk<<2) + kh;
        bf16x8 bv = *(const bf16x8*)(W0s + (size_t)((((int)r<<7) + (c ^ (r&7)))*8));
        acc00 = __builtin_amdgcn_mfma_f32_16x16x32_bf16(a_g0[0][kk], bv, acc00, 0,0,0);
        acc01 = __builtin_amdgcn_mfma_f32_16x16x32_bf16(a_g0[1][kk], bv, acc01, 0,0,0);
      }
    }
    if (doG1){
      #pragma unroll
      for (int kk=0;kk<8;kk++){
        int c = (w<<5) + (kk<<2) + kh;
        bf16x8 bv = *(const bf16x8*)(W1s + (size_t)((((int)r<<8) + (c ^ (r&7)))*8));
        acc10 = __builtin_amdgcn_mfma_f32_16x16x32_bf16(a_g1[0][kk], bv, acc10, 0,0,0);
        acc11 = __builtin_amdgcn_mfma_f32_16x16x32_bf16(a_g1[1][kk], bv, acc11, 0,0,0);
      }
    }
    // ---- one-sync cross-wave reduce + cells ----
    #pragma unroll
    for (int rr=0;rr<4;rr++){
      gl0[w*512 + (kh*4+rr)*16 + r]    = acc00[rr];
      gl0[w*512 + (16+kh*4+rr)*16 + r] = acc01[rr];
      gl1[w*512 + (kh*4+rr)*16 + r]    = acc10[rr];
      gl1[w*512 + (16+kh*4+rr)*16 + r] = acc11[rr];
    }
    __syncthreads();
    if (tid < 128){
      if (doG0){
        float gi=x_gi, gf=x_gf, gg=x_gg, go=x_go;
        #pragma unroll
        for (int ww=0;ww<8;ww++){
          const float* gp = gl0 + ww*512 + cb*16 + cj;
          gi += gp[0]; gf += gp[4]; gg += gp[8]; go += gp[12];
        }
        float cn = sigm(gf)*c0reg + sigm(gi)*ftanh(gg);
        float hn = sigm(go)*ftanh(cn); c0reg = cn;
        hb0[tid] = f2bf(hn);
      }
      if (doG1){
        float gi=b1i, gf=b1f, gg=b1g, go=b1o;
        #pragma unroll
        for (int ww=0;ww<8;ww++){
          const float* gp = gl1 + ww*512 + cb*16 + cj;
          gi += gp[0]; gf += gp[4]; gg += gp[8]; go += gp[12];
        }
        float cn = sigm(gf)*c1reg + sigm(gi)*ftanh(gg);
        float hn = sigm(go)*ftanh(cn); c1reg = cn;
        hb1[tid] = f2bf(hn);
      }
    }
    __syncthreads();
    // ---- packed coherent h stores + q output (tid<32, one u64 each) ----
    if (tid < 32){
      union { u64 v; u16 s[4]; } pk;
      if (doG0){
        pk.s[0]=hb0[tid*4]; pk.s[1]=hb0[tid*4+1]; pk.s[2]=hb0[tid*4+2]; pk.s[3]=hb0[tid*4+3];
        __hip_atomic_store((u64*)(Hcur + (size_t)tid*2048 + bid*4), pk.v,
                           __ATOMIC_RELAXED, __HIP_MEMORY_SCOPE_AGENT);
      }
      if (doG1){
        pk.s[0]=hb1[tid*4]; pk.s[1]=hb1[tid*4+1]; pk.s[2]=hb1[tid*4+2]; pk.s[3]=hb1[tid*4+3];
        __hip_atomic_store((u64*)(Hcur + (size_t)tid*2048 + 1024 + bid*4), pk.v,
                           __ATOMIC_RELAXED, __HIP_MEMORY_SCOPE_AGENT);
        *(u64*)(qcat + ((size_t)(p-1)*32 + tid)*2048 + bid*4) = pk.v;   // q, normal store
      }
    }
    if (p < T_) xcd_barrier(barL, p);
  }
}

// ---------------- persistent attention: 8 blocks/batch x 512 thr (round-6 structure + fast act) ----
__global__ __launch_bounds__(512) void k_attn_p(const u16* __restrict__ vpb, const u16* __restrict__ qpb,
    const u16* __restrict__ enc, const float* __restrict__ convw,
    float* __restrict__ eng, u16* __restrict__ qcat, int* __restrict__ barA)
{
  __shared__ float aw[256];
  __shared__ float red[16];
  __shared__ float cred[512];
  int bid = blockIdx.x, tid = threadIdx.x;
  int b = bid>>3, p = bid&7;
  int w = tid>>6, lane = tid&63;
  int d0 = lane*16;
  f32x4 cw[16];
  #pragma unroll
  for (int j=0;j<16;j++) cw[j] = *(const f32x4*)(convw + (size_t)(d0+j)*4);
  if (tid < 256) aw[tid] = 0.f;
  __syncthreads();
  int* cnt = barA + b*32;
  for (int t=0; t<T_; ++t){
    float* ebuf = eng + (t&1)*8192 + b*256;
    // ---- energy: this block covers s in [p*32, p*32+32); wave w does 4 s ----
    const u16* qrow = qpb + ((size_t)t*32 + b)*1024 + d0;
    bf16x8 q0 = *(const bf16x8*)qrow, q1 = *(const bf16x8*)(qrow+8);
    float qf[16];
    #pragma unroll
    for (int j=0;j<16;j++) qf[j] = bf2f((u16)(j<8 ? q0[j] : q1[j-8]));
    #pragma unroll
    for (int ss=0; ss<4; ++ss){
      int s = p*32 + w*4 + ss;
      float am = (s>0)   ? aw[s-1] : 0.f;
      float ac =           aw[s];
      float ap = (s<255) ? aw[s+1] : 0.f;
      const u16* vrow = vpb + ((size_t)(b*256+s))*1024 + d0;
      bf16x8 v0 = *(const bf16x8*)vrow, v1 = *(const bf16x8*)(vrow+8);
      float sum = 0.f;
      #pragma unroll
      for (int j=0;j<16;j++){
        float vv = bf2f((u16)(j<8 ? v0[j] : v1[j-8]));
        float x = qf[j] + vv + am*cw[j][0] + ac*cw[j][1] + ap*cw[j][2];
        sum += ftanh(x)*cw[j][3];
      }
      #pragma unroll
      for (int o=32;o;o>>=1) sum += __shfl_xor(sum, o);
      if (lane==0)
        __hip_atomic_store(ebuf + s, sum, __ATOMIC_RELAXED, __HIP_MEMORY_SCOPE_AGENT);
    }
    ring_barrier(cnt, 8, t);
    // ---- softmax over 256 (redundant per block, coherent energy loads) ----
    float e_val = -3.0e38f;
    if (tid < 256)
      e_val = __hip_atomic_load(ebuf + tid, __ATOMIC_RELAXED, __HIP_MEMORY_SCOPE_AGENT);
    float m = e_val;
    #pragma unroll
    for (int o=32;o;o>>=1) m = fmaxf(m, __shfl_xor(m,o));
    if (lane==0) red[w] = m;
    __syncthreads();
    float mx = red[0];
    #pragma unroll
    for (int i2=1;i2<8;i2++) mx = fmaxf(mx, red[i2]);
    float ex = (tid < 256) ? __expf(e_val - mx) : 0.f;
    float sl = ex;
    #pragma unroll
    for (int o=32;o;o>>=1) sl += __shfl_xor(sl,o);
    __syncthreads();
    if (lane==0) red[8+w] = sl;
    __syncthreads();
    float st = red[8]+red[9]+red[10]+red[11]+red[12]+red[13]+red[14]+red[15];
    if (tid < 256) aw[tid] = ex * __builtin_amdgcn_rcpf(st);
    __syncthreads();
    // ---- context slice d in [p*128, p*128+128): 4-way s-split ----
    int sq = tid>>7, dt = tid&127;
    const u16* ep = enc + (size_t)(b*256 + sq*64)*1024 + p*128 + dt;
    float a0=0.f,a1=0.f,a2=0.f,a3=0.f;
    #pragma unroll 4
    for (int s2=0;s2<64;s2+=4){
      a0 += aw[sq*64+s2]   * bf2f(ep[(size_t)(s2)  *1024]);
      a1 += aw[sq*64+s2+1] * bf2f(ep[(size_t)(s2+1)*1024]);
      a2 += aw[sq*64+s2+2] * bf2f(ep[(size_t)(s2+2)*1024]);
      a3 += aw[sq*64+s2+3] * bf2f(ep[(size_t)(s2+3)*1024]);
    }
    cred[tid] = a0+a1+a2+a3;
    __syncthreads();
    if (tid < 128)
      qcat[((size_t)t*32 + b)*2048 + 1024 + p*128 + tid] =
        f2bf(cred[tid]+cred[128+tid]+cred[256+tid]+cred[384+tid]);
    __syncthreads();
  }
}

// in-place log_softmax over V per row of out (register-cached, 2 passes of traffic)
__global__ __launch_bounds__(256) void k_logsm(float* __restrict__ out){
  int row = blockIdx.x, tid = threadIdx.x;
  float* p = out + (size_t)row*V_;
  __shared__ float red[4];
  float pv[40];
  int nv = 0;
  float mx = -3.0e38f;
  for (int v=tid; v<V_; v+=256){ float x = p[v]; pv[nv++] = x; mx = fmaxf(mx, x); }
  #pragma unroll
  for (int o=32;o;o>>=1) mx = fmaxf(mx, __shfl_xor(mx,o));
  if ((tid&63)==0) red[tid>>6]=mx;
  __syncthreads();
  mx = fmaxf(fmaxf(red[0],red[1]),fmaxf(red[2],red[3]));
  __syncthreads();
  float s = 0.f;
  for (int i=0;i<nv;i++) s += __expf(pv[i]-mx);
  #pragma unroll
  for (int o=32;o;o>>=1) s += __shfl_xor(s,o);
  if ((tid&63)==0) red[tid>>6]=s;
  __syncthreads();
  float lz = mx + __logf(red[0]+red[1]+red[2]+red[3]);
  { int i=0; for (int v=tid; v<V_; v+=256) p[v] = pv[i++] - lz; }
}

// ---------------- host ----------------
extern "C" void kernel_launch(void* const* d_in, const int* in_sizes, int n_in,
                              void* d_out, int out_size, void* d_ws, size_t ws_size,
                              hipStream_t stream)
{
  const float* enc   = (const float*)d_in[0];
  const int*   tgt   = (const int*)  d_in[1];
  const float* emb   = (const float*)d_in[2];
  const float* Wih   = (const float*)d_in[3];
  const float* Whh   = (const float*)d_in[4];
  const float* bih   = (const float*)d_in[5];
  const float* bhh   = (const float*)d_in[6];
  const float* Wcv   = (const float*)d_in[7];
  const float* bcv   = (const float*)d_in[8];
  const float* Wq    = (const float*)d_in[9];
  const float* Wvm   = (const float*)d_in[10];
  const float* abias = (const float*)d_in[11];
  const float* fcw   = (const float*)d_in[12];
  // d_in[13] fc_attn_b: softmax-invariant, unused
  const float* fc1w  = (const float*)d_in[14];
  const float* fc1b  = (const float*)d_in[15];
  const float* fc2w  = (const float*)d_in[16];
  const float* fc2b  = (const float*)d_in[17];
  float* out = (float*)d_out;

  char* base = (char*)d_ws; size_t off = 0;
  auto A = [&](size_t nbytes)->char*{ char* q = base + off; off += (nbytes + 255) & ~(size_t)255; return q; };
  u16* enc_bf  = (u16*)A(8388608ull*2);
  u16* Wv_bf   = (u16*)A(1048576ull*2);
  u16* Wih0_bf = (u16*)A(4194304ull*2);
  u16* W1cat   = (u16*)A(8388608ull*2);
  u16* Whh0_bf = (u16*)A(4194304ull*2);
  u16* Wq_bf   = (u16*)A(1048576ull*2);
  u16* fc1w_bf = (u16*)A(2097152ull*2);
  u16* fc2w_bf = (u16*)A(10240000ull*2);  // ALSO aliased as Hh during the LSTM phase
  u16* embA    = (u16*)A(4194304ull*2);   // reused: X0-GEMM A -> qpb -> hid
  u16* X0      = (u16*)A(16777216ull*2);  // (T*32, 4096) bf16, includes bias0
  u16* vpb     = (u16*)A(8388608ull*2);   // bf16(vproj + bconv + attn_bias)
  u16* qcat    = (u16*)A(8388608ull*2);   // (T*32, 2048) = [q | context]
  float* bias0 = (float*)A(4096*4);
  float* bias1 = (float*)A(4096*4);
  float* biasE = (float*)A(1024*4);
  float* convw = (float*)A(4096*4);       // [d][{Wc0,Wc1,Wc2,fcw}]
  float* eng   = (float*)A(2*8192*4);     // attn energy double buffer
  int* barL    = (int*)A(4096);           // hierarchical barrier, 128B-padded lines
  int* barA    = (int*)A(4096);           // 32 batches x 32-int (128B) lines
  u16* Hh      = fc2w_bf;                 // 130 slots x (32x2048) bf16 = 17.04 MB <= 20.48 MB
  u16* qpb     = embA;                    // (T*32, 1024) bf16 qp
  u16* hid     = embA;

  // zero h-history slots -1 and 0 + barriers (re-done on every graph replay)
  hipMemsetAsync(Hh, 0, 2*65536*2, stream);
  hipMemsetAsync(barL, 0, 4096, stream);
  hipMemsetAsync(barA, 0, 4096, stream);

  // prep: bf16 casts (fc2w cast DEFERRED until after LSTM+attn; its buffer holds Hh now)
  k_cast<<<2048,256,0,stream>>>(enc,  enc_bf,  8388608);
  k_cast<<<1024,256,0,stream>>>(Wih,  Wih0_bf, 4194304);
  k_cast<<<1024,256,0,stream>>>(Whh,  Whh0_bf, 4194304);
  k_cast<<<512,256,0,stream>>>(Wq,    Wq_bf,   1048576);
  k_cast<<<512,256,0,stream>>>(Wvm,   Wv_bf,   1048576);
  k_cast<<<512,256,0,stream>>>(fc1w,  fc1w_bf, 2097152);
  k_w1cat<<<2048,256,0,stream>>>(Wih + 4194304, Whh + 4194304, W1cat);
  k_bias<<<16,256,0,stream>>>(bih, bhh, bcv, abias, Wcv, fcw, bias0, bias1, biasE, convw);
  k_gather<<<4096,256,0,stream>>>(emb, tgt, embA);

  // vpb = bf16(enc @ Wv^T + (bconv + attn_bias))   (8192 x 1024 x 1024)
  k_gemm128<1,false><<<dim3(8,64),256,0,stream>>>(enc_bf, Wv_bf, biasE, vpb, 8192, 1024, 1024, 1024, 1024);
  // X0 = bf16(emb[targets] @ W_ih0^T + (b_ih0+b_hh0))  (4096 x 4096 x 1024)
  k_gemm128<1,false><<<dim3(32,32),256,0,stream>>>(embA, Wih0_bf, bias0, X0, 4096, 4096, 1024, 1024, 4096);

  // ---- persistent LSTM loop (256 blocks, weights in LDS, hierarchical barrier) ----
  {
    const u16* a0 = Whh0_bf; const u16* a1 = W1cat; const u16* a2 = X0; const float* a3 = bias1;
    u16* a4 = Hh; u16* a5 = qcat; int* a6 = barL;
    void* args[] = {(void*)&a0,(void*)&a1,(void*)&a2,(void*)&a3,(void*)&a4,(void*)&a5,(void*)&a6};
    hipError_t e = hipLaunchCooperativeKernel((const void*)k_lstm_p, dim3(256), dim3(512), args, 0, stream);
    if (e != hipSuccess)
      k_lstm_p<<<dim3(256),dim3(512),0,stream>>>(a0,a1,a2,a3,a4,a5,a6);
  }

  // qp for all steps: (4096 x 1024 x 1024), A = qcat[:, :1024] (lda 2048) -> bf16 qpb
  k_gemm128<1,false><<<dim3(8,32),256,0,stream>>>(qcat, Wq_bf, nullptr, qpb, 4096, 1024, 1024, 2048, 1024);

  // ---- persistent attention loop (256 blocks x 512 thr, per-batch barrier) ----
  {
    const u16* a0 = vpb; const u16* a1 = qpb; const u16* a2 = enc_bf; const float* a3 = convw;
    float* a4 = eng; u16* a5 = qcat; int* a6 = barA;
    void* args[] = {(void*)&a0,(void*)&a1,(void*)&a2,(void*)&a3,(void*)&a4,(void*)&a5,(void*)&a6};
    hipError_t e = hipLaunchCooperativeKernel((const void*)k_attn_p, dim3(256), dim3(512), args, 0, stream);
    if (e != hipSuccess)
      k_attn_p<<<dim3(256),dim3(512),0,stream>>>(a0,a1,a2,a3,a4,a5,a6);
  }

  // hid = tanh(qcat @ fc1w^T + fc1b)   (4096 x 1024 x 2048)
  k_gemm128<2,false><<<dim3(8,32),256,0,stream>>>(qcat, fc1w_bf, fc1b, hid, 4096, 1024, 2048, 2048, 1024);
  // fc2 weight cast (deferred; Hh no longer needed)
  k_cast<<<2048,256,0,stream>>>(fc2w, fc2w_bf, 10240000);
  // logits = hid @ fc2w^T + fc2b -> out[b][t][v]  (4096 x 10000 x 1024, row swizzle (t,b)->(b,t))
  k_gemm128<0,true><<<dim3(79,32),256,0,stream>>>(hid, fc2w_bf, fc2b, out, 4096, V_, 1024, 1024, V_);
  // in-place log_softmax over V
  k_logsm<<<4096,256,0,stream>>>(out);
}